// Round 4
// baseline (392.308 us; speedup 1.0000x reference)
//
#include <hip/hip_runtime.h>

// Problem constants (fixed by setup_inputs)
#define D      1024
#define H      16
#define HD     64
#define SP     32752       // START_POS
#define TT     32768       // total attended keys
#define SCALE  0.125f
#define NC     128         // chunks
#define CHUNK  256         // keys per chunk (NC*CHUNK == TT)
#define PSTR   260         // LDS p-row stride in floats (mult of 4 for b128; 260%32==4)

__device__ __forceinline__ float4 ldg4(const float* p){ return *reinterpret_cast<const float4*>(p); }
__device__ __forceinline__ void   stg4(float* p, float4 v){ *reinterpret_cast<float4*>(p) = v; }

// y[16 x 1024] = x[16 x 1024] @ W^T, one 16-row chunk of W per block (256 thr).
__device__ __forceinline__ float gemm16_val(const float* __restrict__ x,
                                            const float* __restrict__ W,
                                            int ochunk, int* o_out, int* li_out)
{
    const int t  = threadIdx.x;
    const int o  = ochunk * 16 + (t >> 4);
    const int ds = (t & 15) << 6;   // *64

    float4 wv[16];
    const float* wp = W + (size_t)o * D + ds;
    #pragma unroll
    for (int d4 = 0; d4 < 16; ++d4) wv[d4] = ldg4(wp + d4 * 4);

    float a[16];
    #pragma unroll
    for (int i = 0; i < 16; ++i) {
        const float* xp = x + (size_t)i * D + ds;
        float s = 0.f;
        #pragma unroll
        for (int d4 = 0; d4 < 16; ++d4) {
            float4 xv = ldg4(xp + d4 * 4);
            s += wv[d4].x * xv.x + wv[d4].y * xv.y + wv[d4].z * xv.z + wv[d4].w * xv.w;
        }
        a[i] = s;
    }
    #pragma unroll
    for (int off = 8; off >= 1; off >>= 1) {
        #pragma unroll
        for (int i = 0; i < 16; ++i) a[i] += __shfl_xor(a[i], off, 16);
    }
    const int li = t & 15;
    float v = a[0];
    #pragma unroll
    for (int i = 1; i < 16; ++i) v = (li == i) ? a[i] : v;
    *o_out = o; *li_out = li;
    return v;
}

// New K/V rows go to workspace Kn/Vn (cache inputs are read-only).
__global__ __launch_bounds__(256) void qkv_proj(
    const float* __restrict__ q,
    const float* __restrict__ Wq, const float* __restrict__ Wk, const float* __restrict__ Wv,
    float* __restrict__ Qws, float* __restrict__ out,
    float* __restrict__ Kn, float* __restrict__ Vn)
{
    const int m      = blockIdx.x >> 6;   // 0=Q,1=K,2=V
    const int ochunk = blockIdx.x & 63;
    const float* W = (m == 0) ? Wq : (m == 1) ? Wk : Wv;
    int o, li;
    float v = gemm16_val(q, W, ochunk, &o, &li);
    if (m == 0) {
        Qws[li * D + o] = v;
    } else if (m == 1) {
        out[16384 + li * D + o] = v;                 // output 1: K
        Kn[li * D + o] = v;
    } else {
        out[32768 + li * D + o] = v;                 // output 2: V
        Vn[li * D + o] = v;
    }
}

__global__ __launch_bounds__(256) void out_proj(
    const float* __restrict__ O, const float* __restrict__ Wo, float* __restrict__ out)
{
    int o, li;
    float v = gemm16_val(O, Wo, blockIdx.x, &o, &li);
    out[li * D + o] = v;                             // output 0
}

// Flash-decode partials. grid: 16 heads x 128 chunks of 256 keys; 256 thr (4 waves).
// Scores: 1 key/thread, FULL K row preloaded into kv[16] (16 loads in flight).
// PV: 4-row V software-prefetch pipeline (8 loads in flight). Prefetch runs 4 rows
// past the wave's 64-key block; those reads stay inside V for every fast-path block
// (last chunk's jsub=3 takes the slow path) and their values are dead.
__global__ __launch_bounds__(256, 4) void attn_partial(
    const float* __restrict__ Qws, const float* __restrict__ K, const float* __restrict__ V,
    const float* __restrict__ Kn, const float* __restrict__ Vn,
    float* __restrict__ num, float* __restrict__ den)
{
    __shared__ float4 q_s[256];                        // [i][d4] (4 KB)
    __shared__ __align__(16) float p_s[16 * PSTR];     // exp'd scores [i][j]; reused as osum
    __shared__ float den_s[64];                        // [jsub][i]

    const int t     = threadIdx.x;
    const int h     = blockIdx.x & 15;
    const int c     = blockIdx.x >> 4;
    const int cbase = c * CHUNK;

    // stage Q[head] (16x64) into LDS
    {
        const int i = t >> 4, d4 = t & 15;
        q_s[t] = ldg4(Qws + (size_t)i * D + h * HD + d4 * 4);
    }
    __syncthreads();

    // -------- scores phase: thread t <-> key cbase+t; whole K row in regs --------
    {
        const int j0 = cbase + t;
        const float* kp = (j0 < SP) ? (K  + (size_t)j0        * D + h * HD)
                                    : (Kn + (size_t)(j0 - SP) * D + h * HD);
        float4 kv[16];
        #pragma unroll
        for (int d4 = 0; d4 < 16; ++d4) kv[d4] = ldg4(kp + d4 * 4);   // 16 loads in flight

        if (j0 >= SP) {   // causal-mask region (only last chunk's tail)
            #pragma unroll
            for (int i = 0; i < 16; ++i) {
                float s = 0.f;
                #pragma unroll
                for (int d4 = 0; d4 < 16; ++d4) {
                    float4 qv = q_s[i * 16 + d4];      // uniform-address broadcast
                    s += kv[d4].x*qv.x + kv[d4].y*qv.y + kv[d4].z*qv.z + kv[d4].w*qv.w;
                }
                p_s[i * PSTR + t] = (j0 <= SP + i) ? __expf(s * SCALE) : 0.f;
            }
        } else {
            #pragma unroll
            for (int i = 0; i < 16; ++i) {
                float s = 0.f;
                #pragma unroll
                for (int d4 = 0; d4 < 16; ++d4) {
                    float4 qv = q_s[i * 16 + d4];
                    s += kv[d4].x*qv.x + kv[d4].y*qv.y + kv[d4].z*qv.z + kv[d4].w*qv.w;
                }
                p_s[i * PSTR + t] = __expf(s * SCALE);
            }
        }
    }
    __syncthreads();

    // -------- PV phase --------
    const int d4 = t & 15, ig = (t >> 4) & 3, jsub = t >> 6;
    float4 a0 = make_float4(0.f,0.f,0.f,0.f), a1 = a0, a2 = a0, a3 = a0;
    float  e0 = 0.f, e1 = 0.f, e2 = 0.f, e3 = 0.f;
    {
        const int jb = jsub * 64;                      // 64 keys per wave
        const float* vp  = V + (size_t)(cbase + jb) * D + h * HD + d4 * 4;
        const float* p0r = p_s + (4 * ig + 0) * PSTR + jb;
        const float* p1r = p0r + PSTR;
        const float* p2r = p1r + PSTR;
        const float* p3r = p2r + PSTR;

        if (!(c == NC - 1 && jsub == 3)) {             // fast path: all-old keys
            // prime the pipeline with rows 0..3
            float4 c0 = ldg4(vp + 0*D), c1 = ldg4(vp + 1*D),
                   c2 = ldg4(vp + 2*D), c3 = ldg4(vp + 3*D);
            #pragma unroll 4
            for (int j = 0; j < 64; j += 4) {
                const float* nx = vp + (size_t)(j + 4) * D;   // prefetch next 4 rows (safe over-read)
                float4 n0 = ldg4(nx), n1 = ldg4(nx + D),
                       n2 = ldg4(nx + 2*D), n3 = ldg4(nx + 3*D);
                float4 pA = *reinterpret_cast<const float4*>(p0r + j);
                float4 pB = *reinterpret_cast<const float4*>(p1r + j);
                float4 pC = *reinterpret_cast<const float4*>(p2r + j);
                float4 pD = *reinterpret_cast<const float4*>(p3r + j);
                a0.x += pA.x*c0.x + pA.y*c1.x + pA.z*c2.x + pA.w*c3.x;
                a0.y += pA.x*c0.y + pA.y*c1.y + pA.z*c2.y + pA.w*c3.y;
                a0.z += pA.x*c0.z + pA.y*c1.z + pA.z*c2.z + pA.w*c3.z;
                a0.w += pA.x*c0.w + pA.y*c1.w + pA.z*c2.w + pA.w*c3.w;
                a1.x += pB.x*c0.x + pB.y*c1.x + pB.z*c2.x + pB.w*c3.x;
                a1.y += pB.x*c0.y + pB.y*c1.y + pB.z*c2.y + pB.w*c3.y;
                a1.z += pB.x*c0.z + pB.y*c1.z + pB.z*c2.z + pB.w*c3.z;
                a1.w += pB.x*c0.w + pB.y*c1.w + pB.z*c2.w + pB.w*c3.w;
                a2.x += pC.x*c0.x + pC.y*c1.x + pC.z*c2.x + pC.w*c3.x;
                a2.y += pC.x*c0.y + pC.y*c1.y + pC.z*c2.y + pC.w*c3.y;
                a2.z += pC.x*c0.z + pC.y*c1.z + pC.z*c2.z + pC.w*c3.z;
                a2.w += pC.x*c0.w + pC.y*c1.w + pC.z*c2.w + pC.w*c3.w;
                a3.x += pD.x*c0.x + pD.y*c1.x + pD.z*c2.x + pD.w*c3.x;
                a3.y += pD.x*c0.y + pD.y*c1.y + pD.z*c2.y + pD.w*c3.y;
                a3.z += pD.x*c0.z + pD.y*c1.z + pD.z*c2.z + pD.w*c3.z;
                a3.w += pD.x*c0.w + pD.y*c1.w + pD.z*c2.w + pD.w*c3.w;
                e0 += (pA.x + pA.y) + (pA.z + pA.w);
                e1 += (pB.x + pB.y) + (pB.z + pB.w);
                e2 += (pC.x + pC.y) + (pC.z + pC.w);
                e3 += (pD.x + pD.y) + (pD.z + pD.w);
                c0 = n0; c1 = n1; c2 = n2; c3 = n3;
            }
        } else {                                       // last wave of last chunk: new keys from ws
            for (int j = 0; j < 64; ++j) {
                const int jg = cbase + jb + j;
                const float* vr = (jg < SP) ? (vp + (size_t)j * D)
                                            : (Vn + (size_t)(jg - SP) * D + h * HD + d4 * 4);
                float4 vv = ldg4(vr);
                float pa = p0r[j], pb = p1r[j], pc = p2r[j], pd = p3r[j];
                a0.x += pa*vv.x; a0.y += pa*vv.y; a0.z += pa*vv.z; a0.w += pa*vv.w;
                a1.x += pb*vv.x; a1.y += pb*vv.y; a1.z += pb*vv.z; a1.w += pb*vv.w;
                a2.x += pc*vv.x; a2.y += pc*vv.y; a2.z += pc*vv.z; a2.w += pc*vv.w;
                a3.x += pd*vv.x; a3.y += pd*vv.y; a3.z += pd*vv.z; a3.w += pd*vv.w;
                e0 += pa; e1 += pb; e2 += pc; e3 += pd;
            }
        }
    }
    __syncthreads();   // all p_s reads done before reuse as osum

    // jsub partials into LDS (reuse p_s region; 4*1024 floats < 16*PSTR)
    {
        float* ob = p_s + jsub * 1024 + (ig * 16 + d4) * 16;
        stg4(ob + 0,  a0);
        stg4(ob + 4,  a1);
        stg4(ob + 8,  a2);
        stg4(ob + 12, a3);
        if (d4 == 0) {
            den_s[jsub * 16 + ig * 4 + 0] = e0;
            den_s[jsub * 16 + ig * 4 + 1] = e1;
            den_s[jsub * 16 + ig * 4 + 2] = e2;
            den_s[jsub * 16 + ig * 4 + 3] = e3;
        }
    }
    __syncthreads();

    // final cross-jsub reduce + store: thread = (query i, dim-quad dq)
    {
        const int i = t >> 4, dq = t & 15;
        const int off = ((i >> 2) * 16 + dq) * 16 + (i & 3) * 4;
        float4 r0 = *reinterpret_cast<const float4*>(p_s + off);
        float4 r1 = *reinterpret_cast<const float4*>(p_s + 1024 + off);
        float4 r2 = *reinterpret_cast<const float4*>(p_s + 2048 + off);
        float4 r3 = *reinterpret_cast<const float4*>(p_s + 3072 + off);
        float4 o;
        o.x = (r0.x + r1.x) + (r2.x + r3.x);
        o.y = (r0.y + r1.y) + (r2.y + r3.y);
        o.z = (r0.z + r1.z) + (r2.z + r3.z);
        o.w = (r0.w + r1.w) + (r2.w + r3.w);
        stg4(num + ((size_t)(h * NC + c) * 16 + i) * 64 + dq * 4, o);
        if (t < 16)
            den[(h * NC + c) * 16 + t] =
                (den_s[t] + den_s[16 + t]) + (den_s[32 + t] + den_s[48 + t]);
    }
}

// O[i][h*64+d] = sum_c num / sum_c den
__global__ __launch_bounds__(256) void combine(
    const float* __restrict__ num, const float* __restrict__ den, float* __restrict__ O)
{
    const int idx = blockIdx.x * 256 + threadIdx.x;    // [i][h][d]
    const int d  = idx & 63;
    const int hh = (idx >> 6) & 15;
    const int i  = idx >> 10;
    float ns = 0.f, ds = 0.f;
    #pragma unroll 8
    for (int c = 0; c < NC; ++c) {
        ns += num[((size_t)(hh * NC + c) * 16 + i) * 64 + d];
        ds += den[(hh * NC + c) * 16 + i];
    }
    O[idx] = ns / ds;
}

extern "C" void kernel_launch(void* const* d_in, const int* in_sizes, int n_in,
                              void* d_out, int out_size, void* d_ws, size_t ws_size,
                              hipStream_t stream)
{
    (void)in_sizes; (void)n_in; (void)out_size; (void)ws_size;
    const float* q  = (const float*)d_in[0];
    const float* Wq = (const float*)d_in[1];
    const float* Wk = (const float*)d_in[2];
    const float* Wv = (const float*)d_in[3];
    const float* Wo = (const float*)d_in[4];
    const float* ck = (const float*)d_in[5];   // cache_k — read-only
    const float* cv = (const float*)d_in[6];   // cache_v — read-only
    float* out = (float*)d_out;

    float* ws  = (float*)d_ws;
    float* Qws = ws;                                   // 16384
    float* Kn  = ws + 16384;                           // 16384 (new K rows)
    float* Vn  = ws + 32768;                           // 16384 (new V rows)
    float* num = ws + 49152;                           // 16*NC*16*64 = 2097152
    float* den = num + (size_t)16 * NC * 16 * 64;      // 16*NC*16 = 32768
    float* O   = den + (size_t)16 * NC * 16;           // 16384

    qkv_proj    <<<192,     256, 0, stream>>>(q, Wq, Wk, Wv, Qws, out, Kn, Vn);
    attn_partial<<<16 * NC, 256, 0, stream>>>(Qws, ck, cv, Kn, Vn, num, den);
    combine     <<<64,      256, 0, stream>>>(num, den, O);
    out_proj    <<<64,      256, 0, stream>>>(O, Wo, out);
}

// Round 6
// 385.614 us; speedup vs baseline: 1.0174x; 1.0174x over previous
//
#include <hip/hip_runtime.h>

// Problem constants (fixed by setup_inputs)
#define D      1024
#define H      16
#define HD     64
#define SP     32752       // START_POS
#define TT     32768       // total attended keys
#define SCALE  0.125f
#define NC     128         // chunks
#define CHUNK  256         // keys per chunk (NC*CHUNK == TT)
#define PSTR   260         // LDS p-row stride in floats (mult of 4 for b128)

__device__ __forceinline__ float4 ldg4(const float* p){ return *reinterpret_cast<const float4*>(p); }
__device__ __forceinline__ void   stg4(float* p, float4 v){ *reinterpret_cast<float4*>(p) = v; }

// y[16 x 1024] = x[16 x 1024] @ W^T, one 16-row chunk of W per block (256 thr).
__device__ __forceinline__ float gemm16_val(const float* __restrict__ x,
                                            const float* __restrict__ W,
                                            int ochunk, int* o_out, int* li_out)
{
    const int t  = threadIdx.x;
    const int o  = ochunk * 16 + (t >> 4);
    const int ds = (t & 15) << 6;   // *64

    float4 wv[16];
    const float* wp = W + (size_t)o * D + ds;
    #pragma unroll
    for (int d4 = 0; d4 < 16; ++d4) wv[d4] = ldg4(wp + d4 * 4);

    float a[16];
    #pragma unroll
    for (int i = 0; i < 16; ++i) {
        const float* xp = x + (size_t)i * D + ds;
        float s = 0.f;
        #pragma unroll
        for (int d4 = 0; d4 < 16; ++d4) {
            float4 xv = ldg4(xp + d4 * 4);
            s += wv[d4].x * xv.x + wv[d4].y * xv.y + wv[d4].z * xv.z + wv[d4].w * xv.w;
        }
        a[i] = s;
    }
    #pragma unroll
    for (int off = 8; off >= 1; off >>= 1) {
        #pragma unroll
        for (int i = 0; i < 16; ++i) a[i] += __shfl_xor(a[i], off, 16);
    }
    const int li = t & 15;
    float v = a[0];
    #pragma unroll
    for (int i = 1; i < 16; ++i) v = (li == i) ? a[i] : v;
    *o_out = o; *li_out = li;
    return v;
}

// New K/V rows go to workspace Kn/Vn (cache inputs are read-only).
__global__ __launch_bounds__(256) void qkv_proj(
    const float* __restrict__ q,
    const float* __restrict__ Wq, const float* __restrict__ Wk, const float* __restrict__ Wv,
    float* __restrict__ Qws, float* __restrict__ out,
    float* __restrict__ Kn, float* __restrict__ Vn)
{
    const int m      = blockIdx.x >> 6;   // 0=Q,1=K,2=V
    const int ochunk = blockIdx.x & 63;
    const float* W = (m == 0) ? Wq : (m == 1) ? Wk : Wv;
    int o, li;
    float v = gemm16_val(q, W, ochunk, &o, &li);
    if (m == 0) {
        Qws[li * D + o] = v;
    } else if (m == 1) {
        out[16384 + li * D + o] = v;                 // output 1: K
        Kn[li * D + o] = v;
    } else {
        out[32768 + li * D + o] = v;                 // output 2: V
        Vn[li * D + o] = v;
    }
}

__global__ __launch_bounds__(256) void out_proj(
    const float* __restrict__ O, const float* __restrict__ Wo, float* __restrict__ out)
{
    int o, li;
    float v = gemm16_val(O, Wo, blockIdx.x, &o, &li);
    out[li * D + o] = v;                             // output 0
}

// Flash-decode partials. grid: 16 heads x 128 chunks of 256 keys; 256 thr (4 waves).
// Scores: K staged into LDS in 64-key quarters via COALESCED reg-staging
//   (each thread 4x global float4, consecutive lanes -> consecutive addresses;
//    every 64B line requested once). Rotation swizzle slot=(s+row)&15 on the
//   ds_write, matched on the read -> conflict-free b128 both sides.
//   Compute: lane = key, wave = 4 query rows (wave-uniform q_s broadcasts).
// PV: 4-row V software-prefetch pipeline (verified R3). Prefetch overruns 4 rows
//   past the wave's block; stays inside V for all fast-path blocks, values dead.
__global__ __launch_bounds__(256) void attn_partial(
    const float* __restrict__ Qws, const float* __restrict__ K, const float* __restrict__ V,
    const float* __restrict__ Kn, const float* __restrict__ Vn,
    float* __restrict__ num, float* __restrict__ den)
{
    __shared__ float4 k_s[1024];                       // 16 KB: one 64-key quarter of K (rotated rows)
    __shared__ float4 q_s[256];                        // [i][d4] (4 KB)
    __shared__ __align__(16) float p_s[16 * PSTR];     // exp'd scores [i][j]; reused as osum (16.25 KB)
    __shared__ float den_s[64];                        // [jsub][i]

    const int t     = threadIdx.x;
    const int h     = blockIdx.x & 15;
    const int c     = blockIdx.x >> 4;
    const int cbase = c * CHUNK;
    const int w     = t >> 6, l = t & 63;

    // stage Q[head] (16x64) into LDS
    {
        const int i = t >> 4, d4 = t & 15;
        q_s[t] = ldg4(Qws + (size_t)i * D + h * HD + d4 * 4);
    }
    __syncthreads();

    // -------- scores phase: 4 quarters of 64 keys --------
    for (int qtr = 0; qtr < 4; ++qtr) {
        // coalesced load: thread t covers float4 f = k*256+t of the 64x16 tile
        float4 st[4];
        #pragma unroll
        for (int k = 0; k < 4; ++k) {
            const int f  = k * 256 + t;       // 0..1023
            const int jr = f >> 4;            // local row 0..63
            const int s  = f & 15;            // slot 0..15
            const int jg = cbase + qtr * 64 + jr;
            const float* src = (jg < SP) ? (K  + (size_t)jg        * D + h * HD + s * 4)
                                         : (Kn + (size_t)(jg - SP) * D + h * HD + s * 4);
            st[k] = ldg4(src);                // 4 loads in flight
        }
        #pragma unroll
        for (int k = 0; k < 4; ++k) {
            const int f  = k * 256 + t;
            const int jr = f >> 4;
            const int s  = f & 15;
            k_s[jr * 16 + ((s + jr) & 15)] = st[k];   // rotated store
        }
        __syncthreads();

        // compute: lane l = key, wave w = rows w*4..w*4+3
        {
            const int jcol = qtr * 64 + l;
            const int jg   = cbase + jcol;
            float s0 = 0.f, s1 = 0.f, s2 = 0.f, s3 = 0.f;
            #pragma unroll
            for (int d4 = 0; d4 < 16; ++d4) {
                float4 kv = k_s[l * 16 + ((d4 + l) & 15)];
                float4 q0 = q_s[(w * 4 + 0) * 16 + d4];   // wave-uniform broadcasts
                float4 q1 = q_s[(w * 4 + 1) * 16 + d4];
                float4 q2 = q_s[(w * 4 + 2) * 16 + d4];
                float4 q3 = q_s[(w * 4 + 3) * 16 + d4];
                s0 += kv.x*q0.x + kv.y*q0.y + kv.z*q0.z + kv.w*q0.w;
                s1 += kv.x*q1.x + kv.y*q1.y + kv.z*q1.z + kv.w*q1.w;
                s2 += kv.x*q2.x + kv.y*q2.y + kv.z*q2.z + kv.w*q2.w;
                s3 += kv.x*q3.x + kv.y*q3.y + kv.z*q3.z + kv.w*q3.w;
            }
            if (jg >= SP) {   // causal-mask region (only last chunk's tail)
                p_s[(w*4+0) * PSTR + jcol] = (jg <= SP + w*4+0) ? __expf(s0 * SCALE) : 0.f;
                p_s[(w*4+1) * PSTR + jcol] = (jg <= SP + w*4+1) ? __expf(s1 * SCALE) : 0.f;
                p_s[(w*4+2) * PSTR + jcol] = (jg <= SP + w*4+2) ? __expf(s2 * SCALE) : 0.f;
                p_s[(w*4+3) * PSTR + jcol] = (jg <= SP + w*4+3) ? __expf(s3 * SCALE) : 0.f;
            } else {
                p_s[(w*4+0) * PSTR + jcol] = __expf(s0 * SCALE);
                p_s[(w*4+1) * PSTR + jcol] = __expf(s1 * SCALE);
                p_s[(w*4+2) * PSTR + jcol] = __expf(s2 * SCALE);
                p_s[(w*4+3) * PSTR + jcol] = __expf(s3 * SCALE);
            }
        }
        __syncthreads();   // k_s consumed before next quarter restages
    }

    // -------- PV phase --------
    const int d4 = t & 15, ig = (t >> 4) & 3, jsub = w;
    float4 a0 = make_float4(0.f,0.f,0.f,0.f), a1 = a0, a2 = a0, a3 = a0;
    float  e0 = 0.f, e1 = 0.f, e2 = 0.f, e3 = 0.f;
    {
        const int jb = jsub * 64;                      // 64 keys per wave
        const float* vp  = V + (size_t)(cbase + jb) * D + h * HD + d4 * 4;
        const float* p0r = p_s + (4 * ig + 0) * PSTR + jb;
        const float* p1r = p0r + PSTR;
        const float* p2r = p1r + PSTR;
        const float* p3r = p2r + PSTR;

        if (!(c == NC - 1 && jsub == 3)) {             // fast path: all-old keys
            float4 c0 = ldg4(vp + 0*D), c1 = ldg4(vp + 1*D),
                   c2 = ldg4(vp + 2*D), c3 = ldg4(vp + 3*D);
            #pragma unroll 4
            for (int j = 0; j < 64; j += 4) {
                const float* nx = vp + (size_t)(j + 4) * D;   // prefetch next 4 rows (safe over-read)
                float4 n0 = ldg4(nx), n1 = ldg4(nx + D),
                       n2 = ldg4(nx + 2*D), n3 = ldg4(nx + 3*D);
                float4 pA = *reinterpret_cast<const float4*>(p0r + j);
                float4 pB = *reinterpret_cast<const float4*>(p1r + j);
                float4 pC = *reinterpret_cast<const float4*>(p2r + j);
                float4 pD = *reinterpret_cast<const float4*>(p3r + j);
                a0.x += pA.x*c0.x + pA.y*c1.x + pA.z*c2.x + pA.w*c3.x;
                a0.y += pA.x*c0.y + pA.y*c1.y + pA.z*c2.y + pA.w*c3.y;
                a0.z += pA.x*c0.z + pA.y*c1.z + pA.z*c2.z + pA.w*c3.z;
                a0.w += pA.x*c0.w + pA.y*c1.w + pA.z*c2.w + pA.w*c3.w;
                a1.x += pB.x*c0.x + pB.y*c1.x + pB.z*c2.x + pB.w*c3.x;
                a1.y += pB.x*c0.y + pB.y*c1.y + pB.z*c2.y + pB.w*c3.y;
                a1.z += pB.x*c0.z + pB.y*c1.z + pB.z*c2.z + pB.w*c3.z;
                a1.w += pB.x*c0.w + pB.y*c1.w + pB.z*c2.w + pB.w*c3.w;
                a2.x += pC.x*c0.x + pC.y*c1.x + pC.z*c2.x + pC.w*c3.x;
                a2.y += pC.x*c0.y + pC.y*c1.y + pC.z*c2.y + pC.w*c3.y;
                a2.z += pC.x*c0.z + pC.y*c1.z + pC.z*c2.z + pC.w*c3.z;
                a2.w += pC.x*c0.w + pC.y*c1.w + pC.z*c2.w + pC.w*c3.w;
                a3.x += pD.x*c0.x + pD.y*c1.x + pD.z*c2.x + pD.w*c3.x;
                a3.y += pD.x*c0.y + pD.y*c1.y + pD.z*c2.y + pD.w*c3.y;
                a3.z += pD.x*c0.z + pD.y*c1.z + pD.z*c2.z + pD.w*c3.z;
                a3.w += pD.x*c0.w + pD.y*c1.w + pD.z*c2.w + pD.w*c3.w;
                e0 += (pA.x + pA.y) + (pA.z + pA.w);
                e1 += (pB.x + pB.y) + (pB.z + pB.w);
                e2 += (pC.x + pC.y) + (pC.z + pC.w);
                e3 += (pD.x + pD.y) + (pD.z + pD.w);
                c0 = n0; c1 = n1; c2 = n2; c3 = n3;
            }
        } else {                                       // last wave of last chunk: new keys from ws
            for (int j = 0; j < 64; ++j) {
                const int jg = cbase + jb + j;
                const float* vr = (jg < SP) ? (vp + (size_t)j * D)
                                            : (Vn + (size_t)(jg - SP) * D + h * HD + d4 * 4);
                float4 vv = ldg4(vr);
                float pa = p0r[j], pb = p1r[j], pc = p2r[j], pd = p3r[j];
                a0.x += pa*vv.x; a0.y += pa*vv.y; a0.z += pa*vv.z; a0.w += pa*vv.w;
                a1.x += pb*vv.x; a1.y += pb*vv.y; a1.z += pb*vv.z; a1.w += pb*vv.w;
                a2.x += pc*vv.x; a2.y += pc*vv.y; a2.z += pc*vv.z; a2.w += pc*vv.w;
                a3.x += pd*vv.x; a3.y += pd*vv.y; a3.z += pd*vv.z; a3.w += pd*vv.w;
                e0 += pa; e1 += pb; e2 += pc; e3 += pd;
            }
        }
    }
    __syncthreads();   // all p_s reads done before reuse as osum

    // jsub partials into LDS (reuse p_s region; 4*1024 floats < 16*PSTR)
    {
        float* ob = p_s + jsub * 1024 + (ig * 16 + d4) * 16;
        stg4(ob + 0,  a0);
        stg4(ob + 4,  a1);
        stg4(ob + 8,  a2);
        stg4(ob + 12, a3);
        if (d4 == 0) {
            den_s[jsub * 16 + ig * 4 + 0] = e0;
            den_s[jsub * 16 + ig * 4 + 1] = e1;
            den_s[jsub * 16 + ig * 4 + 2] = e2;
            den_s[jsub * 16 + ig * 4 + 3] = e3;
        }
    }
    __syncthreads();

    // final cross-jsub reduce + store: thread = (query i, dim-quad dq)
    {
        const int i = t >> 4, dq = t & 15;
        const int off = ((i >> 2) * 16 + dq) * 16 + (i & 3) * 4;
        float4 r0 = *reinterpret_cast<const float4*>(p_s + off);
        float4 r1 = *reinterpret_cast<const float4*>(p_s + 1024 + off);
        float4 r2 = *reinterpret_cast<const float4*>(p_s + 2048 + off);
        float4 r3 = *reinterpret_cast<const float4*>(p_s + 3072 + off);
        float4 o;
        o.x = (r0.x + r1.x) + (r2.x + r3.x);
        o.y = (r0.y + r1.y) + (r2.y + r3.y);
        o.z = (r0.z + r1.z) + (r2.z + r3.z);
        o.w = (r0.w + r1.w) + (r2.w + r3.w);
        stg4(num + ((size_t)(h * NC + c) * 16 + i) * 64 + dq * 4, o);
        if (t < 16)
            den[(h * NC + c) * 16 + t] =
                (den_s[t] + den_s[16 + t]) + (den_s[32 + t] + den_s[48 + t]);
    }
}

// O[i][h*64+d] = sum_c num / sum_c den
__global__ __launch_bounds__(256) void combine(
    const float* __restrict__ num, const float* __restrict__ den, float* __restrict__ O)
{
    const int idx = blockIdx.x * 256 + threadIdx.x;    // [i][h][d]
    const int d  = idx & 63;
    const int hh = (idx >> 6) & 15;
    const int i  = idx >> 10;
    float ns = 0.f, ds = 0.f;
    #pragma unroll 8
    for (int c = 0; c < NC; ++c) {
        ns += num[((size_t)(hh * NC + c) * 16 + i) * 64 + d];
        ds += den[(hh * NC + c) * 16 + i];
    }
    O[idx] = ns / ds;
}

extern "C" void kernel_launch(void* const* d_in, const int* in_sizes, int n_in,
                              void* d_out, int out_size, void* d_ws, size_t ws_size,
                              hipStream_t stream)
{
    (void)in_sizes; (void)n_in; (void)out_size; (void)ws_size;
    const float* q  = (const float*)d_in[0];
    const float* Wq = (const float*)d_in[1];
    const float* Wk = (const float*)d_in[2];
    const float* Wv = (const float*)d_in[3];
    const float* Wo = (const float*)d_in[4];
    const float* ck = (const float*)d_in[5];   // cache_k — read-only
    const float* cv = (const float*)d_in[6];   // cache_v — read-only
    float* out = (float*)d_out;

    float* ws  = (float*)d_ws;
    float* Qws = ws;                                   // 16384
    float* Kn  = ws + 16384;                           // 16384 (new K rows)
    float* Vn  = ws + 32768;                           // 16384 (new V rows)
    float* num = ws + 49152;                           // 16*NC*16*64 = 2097152
    float* den = num + (size_t)16 * NC * 16 * 64;      // 16*NC*16 = 32768
    float* O   = den + (size_t)16 * NC * 16;           // 16384

    qkv_proj    <<<192,     256, 0, stream>>>(q, Wq, Wk, Wv, Qws, out, Kn, Vn);
    attn_partial<<<16 * NC, 256, 0, stream>>>(Qws, ck, cv, Kn, Vn, num, den);
    combine     <<<64,      256, 0, stream>>>(num, den, O);
    out_proj    <<<64,      256, 0, stream>>>(O, Wo, out);
}

// Round 7
// 380.448 us; speedup vs baseline: 1.0312x; 1.0136x over previous
//
#include <hip/hip_runtime.h>

// Problem constants (fixed by setup_inputs)
#define D      1024
#define H      16
#define HD     64
#define SP     32752       // START_POS
#define TT     32768       // total attended keys
#define SCALE  0.125f
#define NC     128         // chunks
#define CHUNK  256         // keys per chunk (NC*CHUNK == TT)
#define PSTR   260         // LDS p-row stride in floats

__device__ __forceinline__ float4 ldg4(const float* p){ return *reinterpret_cast<const float4*>(p); }
__device__ __forceinline__ void   stg4(float* p, float4 v){ *reinterpret_cast<float4*>(p) = v; }

// y[16 x 1024] = x[16 x 1024] @ W^T, one 16-row chunk of W per block (256 thr).
__device__ __forceinline__ float gemm16_val(const float* __restrict__ x,
                                            const float* __restrict__ W,
                                            int ochunk, int* o_out, int* li_out)
{
    const int t  = threadIdx.x;
    const int o  = ochunk * 16 + (t >> 4);
    const int ds = (t & 15) << 6;   // *64

    float4 wv[16];
    const float* wp = W + (size_t)o * D + ds;
    #pragma unroll
    for (int d4 = 0; d4 < 16; ++d4) wv[d4] = ldg4(wp + d4 * 4);

    float a[16];
    #pragma unroll
    for (int i = 0; i < 16; ++i) {
        const float* xp = x + (size_t)i * D + ds;
        float s = 0.f;
        #pragma unroll
        for (int d4 = 0; d4 < 16; ++d4) {
            float4 xv = ldg4(xp + d4 * 4);
            s += wv[d4].x * xv.x + wv[d4].y * xv.y + wv[d4].z * xv.z + wv[d4].w * xv.w;
        }
        a[i] = s;
    }
    #pragma unroll
    for (int off = 8; off >= 1; off >>= 1) {
        #pragma unroll
        for (int i = 0; i < 16; ++i) a[i] += __shfl_xor(a[i], off, 16);
    }
    const int li = t & 15;
    float v = a[0];
    #pragma unroll
    for (int i = 1; i < 16; ++i) v = (li == i) ? a[i] : v;
    *o_out = o; *li_out = li;
    return v;
}

// New K/V rows go to workspace Kn/Vn (cache inputs are read-only).
__global__ __launch_bounds__(256) void qkv_proj(
    const float* __restrict__ q,
    const float* __restrict__ Wq, const float* __restrict__ Wk, const float* __restrict__ Wv,
    float* __restrict__ Qws, float* __restrict__ out,
    float* __restrict__ Kn, float* __restrict__ Vn)
{
    const int m      = blockIdx.x >> 6;   // 0=Q,1=K,2=V
    const int ochunk = blockIdx.x & 63;
    const float* W = (m == 0) ? Wq : (m == 1) ? Wk : Wv;
    int o, li;
    float v = gemm16_val(q, W, ochunk, &o, &li);
    if (m == 0) {
        Qws[li * D + o] = v;
    } else if (m == 1) {
        out[16384 + li * D + o] = v;                 // output 1: K
        Kn[li * D + o] = v;
    } else {
        out[32768 + li * D + o] = v;                 // output 2: V
        Vn[li * D + o] = v;
    }
}

__global__ __launch_bounds__(256) void out_proj(
    const float* __restrict__ O, const float* __restrict__ Wo, float* __restrict__ out)
{
    int o, li;
    float v = gemm16_val(O, Wo, blockIdx.x, &o, &li);
    out[li * D + o] = v;                             // output 0
}

// Flash-decode partials. grid: 16 heads x 128 chunks of 256 keys; 256 thr (4 waves).
// WAVE-PRIVATE pipeline: wave w owns keys [w*64, w*64+64) end-to-end
// (scores -> p_s columns -> PV), so there are NO __syncthreads in the main
// loops. No barrier => the compiler emits COUNTED vmcnt waits only at the
// ds_write consumers, so next-sub-tile K loads (and PV V prefetches) stay in
// flight across the whole compute stretch (fixes the measured ~25% load-issue
// duty cycle / ~39 outstanding lines per CU that capped us at ~2.2 TB/s).
// Scores: per wave, 4 sub-tiles of 16 keys staged into wave-private
//   double-buffered LDS (rotation swizzle slot=(s+row)&15 on write & read).
//   Lane = (key kl = l&15, query-quad qq = l>>4); q_s reads are 16-lane
//   broadcasts; 4 score accumulators/lane.
// PV: unchanged 4-row V software-prefetch pipeline (verified R3/R6).
__global__ __launch_bounds__(256) void attn_partial(
    const float* __restrict__ Qws, const float* __restrict__ K, const float* __restrict__ V,
    const float* __restrict__ Kn, const float* __restrict__ Vn,
    float* __restrict__ num, float* __restrict__ den)
{
    __shared__ float4 q_s[256];                        // [i][d4] (4 KB)
    __shared__ float4 myk[4][2][256];                  // wave-private K dbuf (32 KB)
    __shared__ __align__(16) float p_s[16 * PSTR];     // exp'd scores [i][j]; reused as osum (16.25 KB)
    __shared__ float den_s[64];                        // [jsub][i]

    const int t     = threadIdx.x;
    const int h     = blockIdx.x & 15;
    const int c     = blockIdx.x >> 4;
    const int cbase = c * CHUNK;
    const int w     = t >> 6, l = t & 63;

    // stage Q[head] (16x64) into LDS
    {
        const int i = t >> 4, d4 = t & 15;
        q_s[t] = ldg4(Qws + (size_t)i * D + h * HD + d4 * 4);
    }
    __syncthreads();   // the ONLY barrier before the epilogue

    // -------- scores: wave-private, software-pipelined over 4 sub-tiles of 16 keys --------
    {
        const int kl    = l & 15;          // key within sub-tile
        const int qq    = l >> 4;          // query quad 0..3
        const int kbase = cbase + w * 64;  // first key of this wave's tile
        // staging coverage: f = k*64 + l -> row = f>>4 (0..15), slot = f&15
        const int row_[4] = { (0*64+l)>>4, (1*64+l)>>4, (2*64+l)>>4, (3*64+l)>>4 };
        const int sl_ = l & 15;            // slot is l&15 for every k

        float4 st[4];
        #pragma unroll
        for (int k = 0; k < 4; ++k) {      // prologue: sub-tile 0 loads
            const int jg = kbase + row_[k];
            const float* src = (jg < SP) ? (K  + (size_t)jg        * D + h * HD + sl_ * 4)
                                         : (Kn + (size_t)(jg - SP) * D + h * HD + sl_ * 4);
            st[k] = ldg4(src);
        }

        for (int s = 0; s < 4; ++s) {
            const int buf = s & 1;
            // write current sub-tile (rotated store)
            #pragma unroll
            for (int k = 0; k < 4; ++k)
                myk[w][buf][row_[k] * 16 + ((sl_ + row_[k]) & 15)] = st[k];
            // issue next sub-tile loads (stay in flight during compute below)
            if (s < 3) {
                #pragma unroll
                for (int k = 0; k < 4; ++k) {
                    const int jg = kbase + (s + 1) * 16 + row_[k];
                    const float* src = (jg < SP) ? (K  + (size_t)jg        * D + h * HD + sl_ * 4)
                                                 : (Kn + (size_t)(jg - SP) * D + h * HD + sl_ * 4);
                    st[k] = ldg4(src);
                }
            }
            // compute scores for this sub-tile: key kl, queries qq*4..qq*4+3
            float a0 = 0.f, a1 = 0.f, a2 = 0.f, a3 = 0.f;
            #pragma unroll
            for (int d4 = 0; d4 < 16; ++d4) {
                float4 kv = myk[w][buf][kl * 16 + ((d4 + kl) & 15)];
                float4 q0 = q_s[(qq * 4 + 0) * 16 + d4];   // 16-lane broadcasts
                float4 q1 = q_s[(qq * 4 + 1) * 16 + d4];
                float4 q2 = q_s[(qq * 4 + 2) * 16 + d4];
                float4 q3 = q_s[(qq * 4 + 3) * 16 + d4];
                a0 += kv.x*q0.x + kv.y*q0.y + kv.z*q0.z + kv.w*q0.w;
                a1 += kv.x*q1.x + kv.y*q1.y + kv.z*q1.z + kv.w*q1.w;
                a2 += kv.x*q2.x + kv.y*q2.y + kv.z*q2.z + kv.w*q2.w;
                a3 += kv.x*q3.x + kv.y*q3.y + kv.z*q3.z + kv.w*q3.w;
            }
            const int jcol = w * 64 + s * 16 + kl;
            const int jg   = cbase + jcol;
            if (jg >= SP) {   // causal-mask region (only last chunk's tail)
                p_s[(qq*4+0) * PSTR + jcol] = (jg <= SP + qq*4+0) ? __expf(a0 * SCALE) : 0.f;
                p_s[(qq*4+1) * PSTR + jcol] = (jg <= SP + qq*4+1) ? __expf(a1 * SCALE) : 0.f;
                p_s[(qq*4+2) * PSTR + jcol] = (jg <= SP + qq*4+2) ? __expf(a2 * SCALE) : 0.f;
                p_s[(qq*4+3) * PSTR + jcol] = (jg <= SP + qq*4+3) ? __expf(a3 * SCALE) : 0.f;
            } else {
                p_s[(qq*4+0) * PSTR + jcol] = __expf(a0 * SCALE);
                p_s[(qq*4+1) * PSTR + jcol] = __expf(a1 * SCALE);
                p_s[(qq*4+2) * PSTR + jcol] = __expf(a2 * SCALE);
                p_s[(qq*4+3) * PSTR + jcol] = __expf(a3 * SCALE);
            }
        }
    }
    // NO barrier: wave w's PV reads only p_s columns [w*64, w*64+64) which it wrote itself.

    // -------- PV phase (wave-private keys, jsub = w) --------
    const int d4 = t & 15, ig = (t >> 4) & 3, jsub = w;
    float4 a0 = make_float4(0.f,0.f,0.f,0.f), a1 = a0, a2 = a0, a3 = a0;
    float  e0 = 0.f, e1 = 0.f, e2 = 0.f, e3 = 0.f;
    {
        const int jb = jsub * 64;                      // this wave's 64 keys
        const float* vp  = V + (size_t)(cbase + jb) * D + h * HD + d4 * 4;
        const float* p0r = p_s + (4 * ig + 0) * PSTR + jb;
        const float* p1r = p0r + PSTR;
        const float* p2r = p1r + PSTR;
        const float* p3r = p2r + PSTR;

        if (!(c == NC - 1 && jsub == 3)) {             // fast path: all-old keys
            float4 c0 = ldg4(vp + 0*D), c1 = ldg4(vp + 1*D),
                   c2 = ldg4(vp + 2*D), c3 = ldg4(vp + 3*D);
            #pragma unroll 4
            for (int j = 0; j < 64; j += 4) {
                const float* nx = vp + (size_t)(j + 4) * D;   // prefetch next 4 rows (safe over-read)
                float4 n0 = ldg4(nx), n1 = ldg4(nx + D),
                       n2 = ldg4(nx + 2*D), n3 = ldg4(nx + 3*D);
                float4 pA = *reinterpret_cast<const float4*>(p0r + j);
                float4 pB = *reinterpret_cast<const float4*>(p1r + j);
                float4 pC = *reinterpret_cast<const float4*>(p2r + j);
                float4 pD = *reinterpret_cast<const float4*>(p3r + j);
                a0.x += pA.x*c0.x + pA.y*c1.x + pA.z*c2.x + pA.w*c3.x;
                a0.y += pA.x*c0.y + pA.y*c1.y + pA.z*c2.y + pA.w*c3.y;
                a0.z += pA.x*c0.z + pA.y*c1.z + pA.z*c2.z + pA.w*c3.z;
                a0.w += pA.x*c0.w + pA.y*c1.w + pA.z*c2.w + pA.w*c3.w;
                a1.x += pB.x*c0.x + pB.y*c1.x + pB.z*c2.x + pB.w*c3.x;
                a1.y += pB.x*c0.y + pB.y*c1.y + pB.z*c2.y + pB.w*c3.y;
                a1.z += pB.x*c0.z + pB.y*c1.z + pB.z*c2.z + pB.w*c3.z;
                a1.w += pB.x*c0.w + pB.y*c1.w + pB.z*c2.w + pB.w*c3.w;
                a2.x += pC.x*c0.x + pC.y*c1.x + pC.z*c2.x + pC.w*c3.x;
                a2.y += pC.x*c0.y + pC.y*c1.y + pC.z*c2.y + pC.w*c3.y;
                a2.z += pC.x*c0.z + pC.y*c1.z + pC.z*c2.z + pC.w*c3.z;
                a2.w += pC.x*c0.w + pC.y*c1.w + pC.z*c2.w + pC.w*c3.w;
                a3.x += pD.x*c0.x + pD.y*c1.x + pD.z*c2.x + pD.w*c3.x;
                a3.y += pD.x*c0.y + pD.y*c1.y + pD.z*c2.y + pD.w*c3.y;
                a3.z += pD.x*c0.z + pD.y*c1.z + pD.z*c2.z + pD.w*c3.z;
                a3.w += pD.x*c0.w + pD.y*c1.w + pD.z*c2.w + pD.w*c3.w;
                e0 += (pA.x + pA.y) + (pA.z + pA.w);
                e1 += (pB.x + pB.y) + (pB.z + pB.w);
                e2 += (pC.x + pC.y) + (pC.z + pC.w);
                e3 += (pD.x + pD.y) + (pD.z + pD.w);
                c0 = n0; c1 = n1; c2 = n2; c3 = n3;
            }
        } else {                                       // last wave of last chunk: new keys from ws
            for (int j = 0; j < 64; ++j) {
                const int jg = cbase + jb + j;
                const float* vr = (jg < SP) ? (vp + (size_t)j * D)
                                            : (Vn + (size_t)(jg - SP) * D + h * HD + d4 * 4);
                float4 vv = ldg4(vr);
                float pa = p0r[j], pb = p1r[j], pc = p2r[j], pd = p3r[j];
                a0.x += pa*vv.x; a0.y += pa*vv.y; a0.z += pa*vv.z; a0.w += pa*vv.w;
                a1.x += pb*vv.x; a1.y += pb*vv.y; a1.z += pb*vv.z; a1.w += pb*vv.w;
                a2.x += pc*vv.x; a2.y += pc*vv.y; a2.z += pc*vv.z; a2.w += pc*vv.w;
                a3.x += pd*vv.x; a3.y += pd*vv.y; a3.z += pd*vv.z; a3.w += pd*vv.w;
                e0 += pa; e1 += pb; e2 += pc; e3 += pd;
            }
        }
    }
    __syncthreads();   // all waves' p_s reads done before reuse as osum

    // jsub partials into LDS (reuse p_s region; 4*1024 floats < 16*PSTR)
    {
        float* ob = p_s + jsub * 1024 + (ig * 16 + d4) * 16;
        stg4(ob + 0,  a0);
        stg4(ob + 4,  a1);
        stg4(ob + 8,  a2);
        stg4(ob + 12, a3);
        if (d4 == 0) {
            den_s[jsub * 16 + ig * 4 + 0] = e0;
            den_s[jsub * 16 + ig * 4 + 1] = e1;
            den_s[jsub * 16 + ig * 4 + 2] = e2;
            den_s[jsub * 16 + ig * 4 + 3] = e3;
        }
    }
    __syncthreads();

    // final cross-jsub reduce + store: thread = (query i, dim-quad dq)
    {
        const int i = t >> 4, dq = t & 15;
        const int off = ((i >> 2) * 16 + dq) * 16 + (i & 3) * 4;
        float4 r0 = *reinterpret_cast<const float4*>(p_s + off);
        float4 r1 = *reinterpret_cast<const float4*>(p_s + 1024 + off);
        float4 r2 = *reinterpret_cast<const float4*>(p_s + 2048 + off);
        float4 r3 = *reinterpret_cast<const float4*>(p_s + 3072 + off);
        float4 o;
        o.x = (r0.x + r1.x) + (r2.x + r3.x);
        o.y = (r0.y + r1.y) + (r2.y + r3.y);
        o.z = (r0.z + r1.z) + (r2.z + r3.z);
        o.w = (r0.w + r1.w) + (r2.w + r3.w);
        stg4(num + ((size_t)(h * NC + c) * 16 + i) * 64 + dq * 4, o);
        if (t < 16)
            den[(h * NC + c) * 16 + t] =
                (den_s[t] + den_s[16 + t]) + (den_s[32 + t] + den_s[48 + t]);
    }
}

// O[i][h*64+d] = sum_c num / sum_c den
__global__ __launch_bounds__(256) void combine(
    const float* __restrict__ num, const float* __restrict__ den, float* __restrict__ O)
{
    const int idx = blockIdx.x * 256 + threadIdx.x;    // [i][h][d]
    const int d  = idx & 63;
    const int hh = (idx >> 6) & 15;
    const int i  = idx >> 10;
    float ns = 0.f, ds = 0.f;
    #pragma unroll 8
    for (int c = 0; c < NC; ++c) {
        ns += num[((size_t)(hh * NC + c) * 16 + i) * 64 + d];
        ds += den[(hh * NC + c) * 16 + i];
    }
    O[idx] = ns / ds;
}

extern "C" void kernel_launch(void* const* d_in, const int* in_sizes, int n_in,
                              void* d_out, int out_size, void* d_ws, size_t ws_size,
                              hipStream_t stream)
{
    (void)in_sizes; (void)n_in; (void)out_size; (void)ws_size;
    const float* q  = (const float*)d_in[0];
    const float* Wq = (const float*)d_in[1];
    const float* Wk = (const float*)d_in[2];
    const float* Wv = (const float*)d_in[3];
    const float* Wo = (const float*)d_in[4];
    const float* ck = (const float*)d_in[5];   // cache_k — read-only
    const float* cv = (const float*)d_in[6];   // cache_v — read-only
    float* out = (float*)d_out;

    float* ws  = (float*)d_ws;
    float* Qws = ws;                                   // 16384
    float* Kn  = ws + 16384;                           // 16384 (new K rows)
    float* Vn  = ws + 32768;                           // 16384 (new V rows)
    float* num = ws + 49152;                           // 16*NC*16*64 = 2097152
    float* den = num + (size_t)16 * NC * 16 * 64;      // 16*NC*16 = 32768
    float* O   = den + (size_t)16 * NC * 16;           // 16384

    qkv_proj    <<<192,     256, 0, stream>>>(q, Wq, Wk, Wv, Qws, out, Kn, Vn);
    attn_partial<<<16 * NC, 256, 0, stream>>>(Qws, ck, cv, Kn, Vn, num, den);
    combine     <<<64,      256, 0, stream>>>(num, den, O);
    out_proj    <<<64,      256, 0, stream>>>(O, Wo, out);
}